// Round 1
// baseline (297.840 us; speedup 1.0000x reference)
//
#include <hip/hip_runtime.h>
#include <hip/hip_bf16.h>

typedef short short8 __attribute__((ext_vector_type(8)));
typedef short short4_t __attribute__((ext_vector_type(4)));
typedef float floatx4 __attribute__((ext_vector_type(4)));

#define DEVI __device__ __forceinline__

// Dims: B=4, T=4096, D=256, E=12 (4x k5, 4x k9, 4x k17), 16384 tokens.
// fp32 in/out; MFMA operands bf16.
//
// fused: 1024 blocks x 256 threads, BM=16, launch_bounds (256,4) -> 4 blk/CU
//   (R3: occupancy 22.6% -> ~45% was the bottleneck; work per wave halved,
//    waves/SIMD doubled 2->4).  x staged to LDS once (fp32->bf16).
//   Chunk = half-expert (K=128), As double-buffered. Bias folded as 25th
//   MFMA chunk; LN from accumulators.
//
// ws: projWT bf16 [12][256f][256d] @ 0         (1,572,864)
//     outWT  bf16 [256f][256k]     @ 1,572,864 (131,072)
//     projbT bf16 [256n][32k]      @ 1,703,936 (16,384)  (k>=12 zero)
//     rWT    bf16 [16e][256d]      @ 1,720,320 (8,192)   (e>=12 zero)

DEVI float bf2f(__hip_bfloat16 v) { return __bfloat162float(v); }
DEVI __hip_bfloat16 f2bf(float v) { return __float2bfloat16(v); }
DEVI unsigned short bfbits(float v) { __hip_bfloat16 b = f2bf(v); return *(unsigned short*)&b; }

// ---------------------------------------------------------------- prep ----
// 209 blocks: 0..191 projW 64x64 transpose tiles, 192..207 outW, 208 misc.
__global__ __launch_bounds__(256) void prep_kernel(
    const float* __restrict__ rW,      // [256][12]
    const float* __restrict__ projW,   // [12][256d][256f]
    const float* __restrict__ outW,    // [256k][256f]
    const float* __restrict__ projb,   // [12][256]
    __hip_bfloat16* __restrict__ projWT,
    __hip_bfloat16* __restrict__ outWT,
    __hip_bfloat16* __restrict__ projbT,
    __hip_bfloat16* __restrict__ rWT)
{
    __shared__ __align__(16) __hip_bfloat16 Tt[64 * 72];
    const int bid = blockIdx.x;
    const int tid = threadIdx.x;

    if (bid == 208) {
#pragma unroll
        for (int k = 0; k < 32; k++)
            projbT[tid * 32 + k] = (k < 12) ? f2bf(projb[k * 256 + tid]) : f2bf(0.f);
#pragma unroll
        for (int e = 0; e < 16; e++)
            rWT[e * 256 + tid] = (e < 12) ? f2bf(rW[tid * 12 + e]) : f2bf(0.f);
        return;
    }
    const float* src;
    __hip_bfloat16* dst;
    if (bid < 192) {
        int e = bid >> 4, ti = (bid & 15) >> 2, tj = bid & 3;
        src = projW + (e << 16) + (ti * 64) * 256 + tj * 64;
        dst = projWT + (e << 16) + (tj * 64) * 256 + ti * 64;
    } else {
        int b3 = bid - 192, ti = b3 >> 2, tj = b3 & 3;
        src = outW + (ti * 64) * 256 + tj * 64;
        dst = outWT + (tj * 64) * 256 + ti * 64;
    }
#pragma unroll
    for (int i = 0; i < 4; i++) {
        int r = i * 16 + (tid >> 4);
        int c4 = (tid & 15) * 4;
        float4 f = *(const float4*)(src + r * 256 + c4);
        Tt[(c4 + 0) * 72 + r] = f2bf(f.x);
        Tt[(c4 + 1) * 72 + r] = f2bf(f.y);
        Tt[(c4 + 2) * 72 + r] = f2bf(f.z);
        Tt[(c4 + 3) * 72 + r] = f2bf(f.w);
    }
    __syncthreads();
#pragma unroll
    for (int i = 0; i < 2; i++) {
        int c = i * 32 + (tid >> 3);
        int r8 = (tid & 7) * 8;
        *(short8*)(dst + c * 256 + r8) = *(const short8*)(Tt + c * 72 + r8);
    }
}

// --------------------------------------------------------------- fused ----
// LDS (27,648 B), 4 blocks/CU:
//   xs    bf16 [32][272] @ 0      (17,408)  x tile incl. 16-row causal halo
//   As    bf16 2x[16][136] @17,408 (8,704)  A chunk dbuf
//   wts_s f32  [16][12]  @ 26,112 (   768)
//   psum  f32  [16][5]   @ 26,880 (   320)
//   psq   f32  [16][5]   @ 27,200 (   320)
//   muA   f32  [16]      @ 27,520   rsA f32 [16] @ 27,584
//   normed bf16 [16][264] @ 0     ( 8,448)  aliases xs after chunk loop

template<int K, int NT>
DEVI void conv_lds(const float* __restrict__ cw,          // [K][256] expert
                   const __hip_bfloat16* __restrict__ xs,
                   int tloc,
                   const float* __restrict__ wts_s, int e,
                   __hip_bfloat16* __restrict__ dst, int d_l, int d_g)
{
    float c[K];
#pragma unroll
    for (int j = 0; j < K; j++) c[j] = cw[j * 256 + d_g];
    float w[K - 1];
#pragma unroll
    for (int i = 0; i < K - 1; i++)
        w[i] = bf2f(xs[(16 + tloc - (K - 1) + i) * 272 + d_g]);
#pragma unroll
    for (int t = 0; t < NT; t++) {
        float nv = bf2f(xs[(16 + tloc + t) * 272 + d_g]);
        float s = nv * c[K - 1];
#pragma unroll
        for (int i = 0; i < K - 1; i++) s += w[i] * c[i];
        dst[(tloc + t) * 136 + d_l] = f2bf(s * wts_s[(tloc + t) * 12 + e]);
#pragma unroll
        for (int i = 0; i + 1 < K - 1; i++) w[i] = w[i + 1];
        w[K - 2] = nv;
    }
}

// M=16 x N=64(wave slice) x K=NKS*32; distance-1 prefetch
template<int NKS>
DEVI void gemm_tile(const __hip_bfloat16* __restrict__ A, int astride,
                    const __hip_bfloat16* __restrict__ Bg, int bstride,
                    floatx4 (&acc)[4], int l16, int quad, int nsl)
{
    const __hip_bfloat16* a0p = A + l16 * astride + quad * 8;
    const __hip_bfloat16* bp  = Bg + (nsl + l16) * bstride + quad * 8;
    short8 a0 = *(const short8*)(a0p);
    short8 b[4];
#pragma unroll
    for (int nt = 0; nt < 4; nt++)
        b[nt] = *(const short8*)(bp + nt * 16 * bstride);
#pragma unroll
    for (int ks = 0; ks < NKS; ks++) {
        short8 na0, nb[4];
        if (ks < NKS - 1) {
            na0 = *(const short8*)(a0p + (ks + 1) * 32);
#pragma unroll
            for (int nt = 0; nt < 4; nt++)
                nb[nt] = *(const short8*)(bp + nt * 16 * bstride + (ks + 1) * 32);
        }
#pragma unroll
        for (int nt = 0; nt < 4; nt++)
            acc[nt] = __builtin_amdgcn_mfma_f32_16x16x32_bf16(a0, b[nt], acc[nt], 0, 0, 0);
        if (ks < NKS - 1) {
            a0 = na0;
#pragma unroll
            for (int nt = 0; nt < 4; nt++) b[nt] = nb[nt];
        }
    }
}

__global__ __launch_bounds__(256, 4) void fused_kernel(
    const float* __restrict__ x,
    const float* __restrict__ ck5, const float* __restrict__ ck9,
    const float* __restrict__ ck17,
    const float* __restrict__ rb,      // [12]
    const float* __restrict__ gmm, const float* __restrict__ bta,
    const float* __restrict__ outb,
    const __hip_bfloat16* __restrict__ projWT,
    const __hip_bfloat16* __restrict__ outWT,
    const __hip_bfloat16* __restrict__ projbT,
    const __hip_bfloat16* __restrict__ rWT,
    float* __restrict__ out)
{
    __shared__ __align__(16) char smem[27648];
    __hip_bfloat16* xs = (__hip_bfloat16*)smem;            // [32][272]
    __hip_bfloat16* As = (__hip_bfloat16*)(smem + 17408);  // 2 x [16][136]
    float* wts_s = (float*)(smem + 26112);
    float* psum  = (float*)(smem + 26880);
    float* psq   = (float*)(smem + 27200);
    float* muA   = (float*)(smem + 27520);
    float* rsA   = (float*)(smem + 27584);
    __hip_bfloat16* normed = (__hip_bfloat16*)smem;        // [16][264] later

    const int tid  = threadIdx.x;
    const int wave = tid >> 6;
    const int lane = tid & 63;
    const int quad = lane >> 4;
    const int l16  = lane & 15;
    const int nsl  = wave * 64;                // n-slice base
    const int m0   = blockIdx.x * 16;
    const int bb   = m0 >> 12;
    const int t0   = m0 & 4095;

    // ---- stage x tile rows t0-16..t0+15, fp32 -> bf16 ----
    {
        const float* xb = x + (size_t)bb * 4096 * 256;
        for (int idx = tid; idx < 32 * 64; idx += 256) {
            int row = idx >> 6, c4 = (idx & 63) << 2;
            int gt = t0 - 16 + row;
            short4_t v = {0, 0, 0, 0};
            if (gt >= 0) {
                float4 f = *(const float4*)(xb + (size_t)gt * 256 + c4);
                v[0] = (short)bfbits(f.x); v[1] = (short)bfbits(f.y);
                v[2] = (short)bfbits(f.z); v[3] = (short)bfbits(f.w);
            }
            *(short4_t*)(xs + row * 272 + c4) = v;
        }
    }
    __syncthreads();

    // ---- router (wave 0): MFMA logits + shuffle softmax ----
    if (wave == 0) {
        floatx4 ra = {0.f, 0.f, 0.f, 0.f};
        const __hip_bfloat16* ap = xs + (16 + l16) * 272 + quad * 8;
        const __hip_bfloat16* bp = rWT + l16 * 256 + quad * 8;
#pragma unroll
        for (int kk = 0; kk < 256; kk += 32)
            ra = __builtin_amdgcn_mfma_f32_16x16x32_bf16(
                *(const short8*)(ap + kk), *(const short8*)(bp + kk), ra, 0, 0, 0);
        float rbv = (l16 < 12) ? rb[l16] : 0.f;
#pragma unroll
        for (int r = 0; r < 4; r++) {
            float v = (l16 < 12) ? (ra[r] + rbv) : -1e30f;
            float mx = v;
            mx = fmaxf(mx, __shfl_xor(mx, 1));
            mx = fmaxf(mx, __shfl_xor(mx, 2));
            mx = fmaxf(mx, __shfl_xor(mx, 4));
            mx = fmaxf(mx, __shfl_xor(mx, 8));
            float ex = (l16 < 12) ? __expf(v - mx) : 0.f;
            float sm = ex;
            sm += __shfl_xor(sm, 1);
            sm += __shfl_xor(sm, 2);
            sm += __shfl_xor(sm, 4);
            sm += __shfl_xor(sm, 8);
            if (l16 < 12) wts_s[(quad * 4 + r) * 12 + l16] = ex / sm;
        }
    }
    __syncthreads();

    // producer chunk: c<24: e=c>>1, h=c&1; c==24: bias chunk (A = router wts)
    auto produce = [&](int c) {
        __hip_bfloat16* dst = As + (c & 1) * (16 * 136);
        if (c == 24) {
            if (tid < 128) {
                int t = tid >> 3, k4 = (tid & 7) * 4;
                short4_t v;
#pragma unroll
                for (int j = 0; j < 4; j++) {
                    int k = k4 + j;
                    v[j] = (k < 12) ? (short)bfbits(wts_s[t * 12 + k]) : (short)0;
                }
                *(short4_t*)(dst + t * 136 + k4) = v;
            }
        } else {
            int e = c >> 1, h = c & 1;
            int d_l = tid & 127, tloc = (tid >> 7) * 8;
            int d_g = h * 128 + d_l;
            if (e < 4)
                conv_lds<5, 8>(ck5 + e * 5 * 256, xs, tloc, wts_s, e, dst, d_l, d_g);
            else if (e < 8)
                conv_lds<9, 8>(ck9 + (e - 4) * 9 * 256, xs, tloc, wts_s, e, dst, d_l, d_g);
            else
                conv_lds<17, 8>(ck17 + (e - 8) * 17 * 256, xs, tloc, wts_s, e, dst, d_l, d_g);
        }
    };

    floatx4 acc[4];
#pragma unroll
    for (int j = 0; j < 4; j++) acc[j] = {0.f, 0.f, 0.f, 0.f};

    produce(0);
    __syncthreads();

#pragma unroll 1
    for (int c = 0; c < 25; c++) {
        if (c < 24) {
            produce(c + 1);
            int e = c >> 1, h = c & 1;
            gemm_tile<4>(As + (c & 1) * (16 * 136), 136,
                         projWT + (e << 16) + h * 128, 256, acc, l16, quad, nsl);
        } else {
            gemm_tile<1>(As + (c & 1) * (16 * 136), 136,
                         projbT, 32, acc, l16, quad, nsl);
        }
        __syncthreads();
    }

    // ---- LN stats from accumulators (exact fp32) ----
    {
        float s[4], s2[4];
#pragma unroll
        for (int r = 0; r < 4; r++) {
            float v = 0.f, q = 0.f;
#pragma unroll
            for (int nt = 0; nt < 4; nt++) {
                float a = acc[nt][r];
                v += a; q += a * a;
            }
            s[r] = v; s2[r] = q;
        }
#pragma unroll
        for (int m = 1; m <= 8; m <<= 1)
#pragma unroll
            for (int i = 0; i < 4; i++) {
                s[i]  += __shfl_xor(s[i], m);
                s2[i] += __shfl_xor(s2[i], m);
            }
#pragma unroll
        for (int i = 0; i < 4; i++)
            if (l16 == i) {
                int row = quad * 4 + i;
                psum[row * 5 + wave] = s[i];
                psq[row * 5 + wave]  = s2[i];
            }
    }
    __syncthreads();
    if (tid < 16) {
        float ss = 0.f, qq = 0.f;
#pragma unroll
        for (int p = 0; p < 4; p++) { ss += psum[tid * 5 + p]; qq += psq[tid * 5 + p]; }
        float mu = ss * 0.00390625f;
        float var = fmaxf(qq * 0.00390625f - mu * mu, 0.f);
        muA[tid] = mu;
        rsA[tid] = rsqrtf(var + 1e-5f);
    }
    __syncthreads();

    // ---- normalize acc -> normed bf16 [16][264] (aliases xs) ----
#pragma unroll
    for (int nt = 0; nt < 4; nt++) {
        int col = nsl + nt * 16 + l16;
        float g = gmm[col], bt = bta[col];
#pragma unroll
        for (int r = 0; r < 4; r++) {
            int row = quad * 4 + r;
            normed[row * 264 + col] =
                f2bf((acc[nt][r] - muA[row]) * rsA[row] * g + bt);
        }
    }
    __syncthreads();

    // ---- out = normed @ out_W + out_b ----
    floatx4 acc2[4];
#pragma unroll
    for (int j = 0; j < 4; j++) acc2[j] = {0.f, 0.f, 0.f, 0.f};
    gemm_tile<8>(normed, 264, outWT, 256, acc2, l16, quad, nsl);

    float* op = out + (size_t)m0 * 256;
#pragma unroll
    for (int nt = 0; nt < 4; nt++) {
        int col = nsl + nt * 16 + l16;
        float ob = outb[col];
#pragma unroll
        for (int r = 0; r < 4; r++) {
            int row = quad * 4 + r;
            op[row * 256 + col] = acc2[nt][r] + ob;
        }
    }
}

// -------------------------------------------------------------- launch ----
extern "C" void kernel_launch(void* const* d_in, const int* in_sizes, int n_in,
                              void* d_out, int out_size, void* d_ws, size_t ws_size,
                              hipStream_t stream)
{
    (void)in_sizes; (void)n_in; (void)out_size; (void)ws_size;
    const float* x     = (const float*)d_in[0];
    const float* ck5   = (const float*)d_in[1];
    const float* ck9   = (const float*)d_in[2];
    const float* ck17  = (const float*)d_in[3];
    const float* projW = (const float*)d_in[4];
    const float* projb = (const float*)d_in[5];
    const float* rW    = (const float*)d_in[6];
    const float* rb    = (const float*)d_in[7];
    const float* outW  = (const float*)d_in[8];
    const float* outb  = (const float*)d_in[9];
    const float* gmm   = (const float*)d_in[10];
    const float* bta   = (const float*)d_in[11];

    __hip_bfloat16* projWT = (__hip_bfloat16*)d_ws;
    __hip_bfloat16* outWT  = (__hip_bfloat16*)((char*)d_ws + 1572864);
    __hip_bfloat16* projbT = (__hip_bfloat16*)((char*)d_ws + 1703936);
    __hip_bfloat16* rWT    = (__hip_bfloat16*)((char*)d_ws + 1720320);

    prep_kernel<<<dim3(209), dim3(256), 0, stream>>>(
        rW, projW, outW, projb, projWT, outWT, projbT, rWT);
    fused_kernel<<<dim3(1024), dim3(256), 0, stream>>>(
        x, ck5, ck9, ck17, rb, gmm, bta, outb,
        projWT, outWT, projbT, rWT, (float*)d_out);
}

// Round 2
// 222.355 us; speedup vs baseline: 1.3395x; 1.3395x over previous
//
#include <hip/hip_runtime.h>
#include <hip/hip_bf16.h>

typedef short short8 __attribute__((ext_vector_type(8)));
typedef short short4_t __attribute__((ext_vector_type(4)));
typedef float floatx4 __attribute__((ext_vector_type(4)));

#define DEVI __device__ __forceinline__

// Dims: B=4, T=4096, D=256, E=12 (4x k5, 4x k9, 4x k17), 16384 tokens.
// fp32 in/out; MFMA operands bf16.
//
// R2: back to R0 shape (BM=32, 512 blocks, (256,2)) — R1 showed occupancy
//   was NOT the bound; B-load latency is. New: whole-chunk register
//   prefetch of B (projWT), explicitly double-buffered via manual 2x loop
//   unroll. B loads issue a full produce+gemm+barrier ahead of their MFMA
//   consumer, so the ~250cy L2 latency is covered by conv VALU work.
//
// ws: projWT bf16 [12][256f][256d] @ 0         (1,572,864)
//     outWT  bf16 [256f][256k]     @ 1,572,864 (131,072)
//     projbT bf16 [256n][32k]      @ 1,703,936 (16,384)  (k>=12 zero)
//     rWT    bf16 [16e][256d]      @ 1,720,320 (8,192)   (e>=12 zero)

DEVI float bf2f(__hip_bfloat16 v) { return __bfloat162float(v); }
DEVI __hip_bfloat16 f2bf(float v) { return __float2bfloat16(v); }
DEVI unsigned short bfbits(float v) { __hip_bfloat16 b = f2bf(v); return *(unsigned short*)&b; }

// ---------------------------------------------------------------- prep ----
// 209 blocks: 0..191 projW 64x64 transpose tiles, 192..207 outW, 208 misc.
__global__ __launch_bounds__(256) void prep_kernel(
    const float* __restrict__ rW,      // [256][12]
    const float* __restrict__ projW,   // [12][256d][256f]
    const float* __restrict__ outW,    // [256k][256f]
    const float* __restrict__ projb,   // [12][256]
    __hip_bfloat16* __restrict__ projWT,
    __hip_bfloat16* __restrict__ outWT,
    __hip_bfloat16* __restrict__ projbT,
    __hip_bfloat16* __restrict__ rWT)
{
    __shared__ __align__(16) __hip_bfloat16 Tt[64 * 72];
    const int bid = blockIdx.x;
    const int tid = threadIdx.x;

    if (bid == 208) {
#pragma unroll
        for (int k = 0; k < 32; k++)
            projbT[tid * 32 + k] = (k < 12) ? f2bf(projb[k * 256 + tid]) : f2bf(0.f);
#pragma unroll
        for (int e = 0; e < 16; e++)
            rWT[e * 256 + tid] = (e < 12) ? f2bf(rW[tid * 12 + e]) : f2bf(0.f);
        return;
    }
    const float* src;
    __hip_bfloat16* dst;
    if (bid < 192) {
        int e = bid >> 4, ti = (bid & 15) >> 2, tj = bid & 3;
        src = projW + (e << 16) + (ti * 64) * 256 + tj * 64;
        dst = projWT + (e << 16) + (tj * 64) * 256 + ti * 64;
    } else {
        int b3 = bid - 192, ti = b3 >> 2, tj = b3 & 3;
        src = outW + (ti * 64) * 256 + tj * 64;
        dst = outWT + (tj * 64) * 256 + ti * 64;
    }
#pragma unroll
    for (int i = 0; i < 4; i++) {
        int r = i * 16 + (tid >> 4);
        int c4 = (tid & 15) * 4;
        float4 f = *(const float4*)(src + r * 256 + c4);
        Tt[(c4 + 0) * 72 + r] = f2bf(f.x);
        Tt[(c4 + 1) * 72 + r] = f2bf(f.y);
        Tt[(c4 + 2) * 72 + r] = f2bf(f.z);
        Tt[(c4 + 3) * 72 + r] = f2bf(f.w);
    }
    __syncthreads();
#pragma unroll
    for (int i = 0; i < 2; i++) {
        int c = i * 32 + (tid >> 3);
        int r8 = (tid & 7) * 8;
        *(short8*)(dst + c * 256 + r8) = *(const short8*)(Tt + c * 72 + r8);
    }
}

// --------------------------------------------------------------- fused ----
// LDS (46,592 B):
//   xs    bf16 [48][272] @ 0      (26,112)  x tile incl. 16-row causal halo
//   As    bf16 2x[32][136] @26,112 (17,408) A chunk dbuf
//   wts_s f32  [32][12]  @ 43,520 ( 1,536)
//   psum  f32  [32][5]   @ 45,056 (   640)
//   psq   f32  [32][5]   @ 45,696 (   640)
//   muA   f32  [32]      @ 46,336   rsA f32 [32] @ 46,464
//   normed bf16 [32][264] @ 0     (16,896)  aliases xs after chunk loop

template<int K>
DEVI void conv_lds(const float* __restrict__ cw,          // [K][256] expert
                   const __hip_bfloat16* __restrict__ xs,
                   int tloc,
                   const float* __restrict__ wts_s, int e,
                   __hip_bfloat16* __restrict__ dst, int d_l, int d_g)
{
    float c[K];
#pragma unroll
    for (int j = 0; j < K; j++) c[j] = cw[j * 256 + d_g];
    float w[K - 1];
#pragma unroll
    for (int i = 0; i < K - 1; i++)
        w[i] = bf2f(xs[(16 + tloc - (K - 1) + i) * 272 + d_g]);
#pragma unroll
    for (int t = 0; t < 16; t++) {
        float nv = bf2f(xs[(16 + tloc + t) * 272 + d_g]);
        float s = nv * c[K - 1];
#pragma unroll
        for (int i = 0; i < K - 1; i++) s += w[i] * c[i];
        dst[(tloc + t) * 136 + d_l] = f2bf(s * wts_s[(tloc + t) * 12 + e]);
#pragma unroll
        for (int i = 0; i + 1 < K - 1; i++) w[i] = w[i + 1];
        w[K - 2] = nv;
    }
}

// GEMM with register-preloaded B: M=32 x N=64(wave slice) x K=NKS*32.
// A from LDS (distance-1 prefetch), B already in VGPRs.
template<int NKS>
DEVI void gemm_pre(const __hip_bfloat16* __restrict__ A, int astride,
                   const short8 (&B)[4][4], floatx4 (&acc)[2][4],
                   int l16, int quad)
{
    const __hip_bfloat16* a0p = A + l16 * astride + quad * 8;
    const __hip_bfloat16* a1p = a0p + 16 * astride;
    short8 a0 = *(const short8*)(a0p);
    short8 a1 = *(const short8*)(a1p);
#pragma unroll
    for (int ks = 0; ks < NKS; ks++) {
        short8 na0, na1;
        if (ks < NKS - 1) {
            na0 = *(const short8*)(a0p + (ks + 1) * 32);
            na1 = *(const short8*)(a1p + (ks + 1) * 32);
        }
#pragma unroll
        for (int nt = 0; nt < 4; nt++) {
            acc[0][nt] = __builtin_amdgcn_mfma_f32_16x16x32_bf16(a0, B[ks][nt], acc[0][nt], 0, 0, 0);
            acc[1][nt] = __builtin_amdgcn_mfma_f32_16x16x32_bf16(a1, B[ks][nt], acc[1][nt], 0, 0, 0);
        }
        if (ks < NKS - 1) { a0 = na0; a1 = na1; }
    }
}

// Old inline-B GEMM, kept for the one-shot out-projection.
template<int NKS>
DEVI void gemm_tile(const __hip_bfloat16* __restrict__ A, int astride,
                    const __hip_bfloat16* __restrict__ Bg, int bstride,
                    floatx4 (&acc)[2][4], int l16, int quad, int nsl)
{
    const __hip_bfloat16* a0p = A + l16 * astride + quad * 8;
    const __hip_bfloat16* a1p = a0p + 16 * astride;
    const __hip_bfloat16* bp  = Bg + (nsl + l16) * bstride + quad * 8;
    short8 a0 = *(const short8*)(a0p);
    short8 a1 = *(const short8*)(a1p);
    short8 b[4];
#pragma unroll
    for (int nt = 0; nt < 4; nt++)
        b[nt] = *(const short8*)(bp + nt * 16 * bstride);
#pragma unroll
    for (int ks = 0; ks < NKS; ks++) {
        short8 na0, na1, nb[4];
        if (ks < NKS - 1) {
            na0 = *(const short8*)(a0p + (ks + 1) * 32);
            na1 = *(const short8*)(a1p + (ks + 1) * 32);
#pragma unroll
            for (int nt = 0; nt < 4; nt++)
                nb[nt] = *(const short8*)(bp + nt * 16 * bstride + (ks + 1) * 32);
        }
#pragma unroll
        for (int nt = 0; nt < 4; nt++) {
            acc[0][nt] = __builtin_amdgcn_mfma_f32_16x16x32_bf16(a0, b[nt], acc[0][nt], 0, 0, 0);
            acc[1][nt] = __builtin_amdgcn_mfma_f32_16x16x32_bf16(a1, b[nt], acc[1][nt], 0, 0, 0);
        }
        if (ks < NKS - 1) {
            a0 = na0; a1 = na1;
#pragma unroll
            for (int nt = 0; nt < 4; nt++) b[nt] = nb[nt];
        }
    }
}

__global__ __launch_bounds__(256, 2) void fused_kernel(
    const float* __restrict__ x,
    const float* __restrict__ ck5, const float* __restrict__ ck9,
    const float* __restrict__ ck17,
    const float* __restrict__ rb,      // [12]
    const float* __restrict__ gmm, const float* __restrict__ bta,
    const float* __restrict__ outb,
    const __hip_bfloat16* __restrict__ projWT,
    const __hip_bfloat16* __restrict__ outWT,
    const __hip_bfloat16* __restrict__ projbT,
    const __hip_bfloat16* __restrict__ rWT,
    float* __restrict__ out)
{
    __shared__ __align__(16) char smem[46592];
    __hip_bfloat16* xs = (__hip_bfloat16*)smem;       // [48][272]
    __hip_bfloat16* As = (__hip_bfloat16*)(smem + 26112);  // 2 x [32][136]
    float* wts_s = (float*)(smem + 43520);
    float* psum  = (float*)(smem + 45056);
    float* psq   = (float*)(smem + 45696);
    float* muA   = (float*)(smem + 46336);
    float* rsA   = (float*)(smem + 46464);
    __hip_bfloat16* normed = (__hip_bfloat16*)smem;   // [32][264] later

    const int tid  = threadIdx.x;
    const int wave = tid >> 6;
    const int lane = tid & 63;
    const int quad = lane >> 4;
    const int l16  = lane & 15;
    const int nsl  = wave * 64;                // n-slice base
    const int m0   = blockIdx.x * 32;
    const int bb   = m0 >> 12;
    const int t0   = m0 & 4095;

    // ---- stage x tile rows t0-16..t0+31, fp32 -> bf16 ----
    {
        const float* xb = x + (size_t)bb * 4096 * 256;
        for (int idx = tid; idx < 48 * 64; idx += 256) {
            int row = idx >> 6, c4 = (idx & 63) << 2;
            int gt = t0 - 16 + row;
            short4_t v = {0, 0, 0, 0};
            if (gt >= 0) {
                float4 f = *(const float4*)(xb + (size_t)gt * 256 + c4);
                v[0] = (short)bfbits(f.x); v[1] = (short)bfbits(f.y);
                v[2] = (short)bfbits(f.z); v[3] = (short)bfbits(f.w);
            }
            *(short4_t*)(xs + row * 272 + c4) = v;
        }
    }
    __syncthreads();

    // ---- router (waves 0,1): MFMA logits + shuffle softmax ----
    if (wave < 2) {
        floatx4 ra = {0.f, 0.f, 0.f, 0.f};
        const __hip_bfloat16* ap = xs + (16 + wave * 16 + l16) * 272 + quad * 8;
        const __hip_bfloat16* bp = rWT + l16 * 256 + quad * 8;
#pragma unroll
        for (int kk = 0; kk < 256; kk += 32)
            ra = __builtin_amdgcn_mfma_f32_16x16x32_bf16(
                *(const short8*)(ap + kk), *(const short8*)(bp + kk), ra, 0, 0, 0);
        float rbv = (l16 < 12) ? rb[l16] : 0.f;
#pragma unroll
        for (int r = 0; r < 4; r++) {
            float v = (l16 < 12) ? (ra[r] + rbv) : -1e30f;
            float mx = v;
            mx = fmaxf(mx, __shfl_xor(mx, 1));
            mx = fmaxf(mx, __shfl_xor(mx, 2));
            mx = fmaxf(mx, __shfl_xor(mx, 4));
            mx = fmaxf(mx, __shfl_xor(mx, 8));
            float ex = (l16 < 12) ? __expf(v - mx) : 0.f;
            float sm = ex;
            sm += __shfl_xor(sm, 1);
            sm += __shfl_xor(sm, 2);
            sm += __shfl_xor(sm, 4);
            sm += __shfl_xor(sm, 8);
            if (l16 < 12) wts_s[(wave * 16 + quad * 4 + r) * 12 + l16] = ex / sm;
        }
    }
    __syncthreads();

    // producer chunk: c<24: e=c>>1, h=c&1; c==24: bias chunk (A = router wts)
    auto produce = [&](int c) {
        __hip_bfloat16* dst = As + (c & 1) * (32 * 136);
        if (c == 24) {
            int t = tid >> 3, k4 = (tid & 7) * 4;
            short4_t v;
#pragma unroll
            for (int j = 0; j < 4; j++) {
                int k = k4 + j;
                v[j] = (k < 12) ? (short)bfbits(wts_s[t * 12 + k]) : (short)0;
            }
            *(short4_t*)(dst + t * 136 + k4) = v;
        } else {
            int e = c >> 1, h = c & 1;
            int d_l = tid & 127, tloc = (tid >> 7) * 16;
            int d_g = h * 128 + d_l;
            if (e < 4)
                conv_lds<5>(ck5 + e * 5 * 256, xs, tloc, wts_s, e, dst, d_l, d_g);
            else if (e < 8)
                conv_lds<9>(ck9 + (e - 4) * 9 * 256, xs, tloc, wts_s, e, dst, d_l, d_g);
            else
                conv_lds<17>(ck17 + (e - 8) * 17 * 256, xs, tloc, wts_s, e, dst, d_l, d_g);
        }
    };

    // whole-chunk register prefetch of B (two explicit buffers, no runtime
    // reg-array indexing). Chunk c<24: projWT panel; c==24: projbT (ks 0 only).
    short8 BregA[4][4], BregB[4][4];
    auto loadB = [&](short8 (&B)[4][4], int c) {
        if (c < 24) {
            int e = c >> 1, h = c & 1;
            const __hip_bfloat16* bp =
                projWT + (e << 16) + h * 128 + (nsl + l16) * 256 + quad * 8;
#pragma unroll
            for (int ks = 0; ks < 4; ks++)
#pragma unroll
                for (int nt = 0; nt < 4; nt++)
                    B[ks][nt] = *(const short8*)(bp + nt * 16 * 256 + ks * 32);
        } else {
            const __hip_bfloat16* bp = projbT + (nsl + l16) * 32 + quad * 8;
#pragma unroll
            for (int nt = 0; nt < 4; nt++)
                B[0][nt] = *(const short8*)(bp + nt * 16 * 32);
        }
    };

    floatx4 acc[2][4];
#pragma unroll
    for (int i = 0; i < 2; i++)
#pragma unroll
        for (int j = 0; j < 4; j++) acc[i][j] = {0.f, 0.f, 0.f, 0.f};

    loadB(BregA, 0);
    produce(0);
    __syncthreads();

    // 12 pairs of chunks; B for chunk c issued one full half-iteration early.
#pragma unroll 1
    for (int cc = 0; cc < 12; cc++) {
        int c0 = cc * 2;
        loadB(BregB, c0 + 1);
        produce(c0 + 1);
        gemm_pre<4>(As + 0, 136, BregA, acc, l16, quad);
        __syncthreads();
        loadB(BregA, c0 + 2);              // cc==11 -> bias B (projbT)
        produce(c0 + 2);                   // cc==11 -> bias chunk into buf 0
        gemm_pre<4>(As + (32 * 136), 136, BregB, acc, l16, quad);
        __syncthreads();
    }
    // bias chunk c=24 (As buf 0, BregA[0][*])
    gemm_pre<1>(As + 0, 136, BregA, acc, l16, quad);

    // ---- LN stats from accumulators (exact fp32) ----
    {
        float s[8], s2[8];
#pragma unroll
        for (int mf = 0; mf < 2; mf++)
#pragma unroll
            for (int r = 0; r < 4; r++) {
                int i = mf * 4 + r;
                float v = 0.f, q = 0.f;
#pragma unroll
                for (int nt = 0; nt < 4; nt++) {
                    float a = acc[mf][nt][r];
                    v += a; q += a * a;
                }
                s[i] = v; s2[i] = q;
            }
#pragma unroll
        for (int m = 1; m <= 8; m <<= 1)
#pragma unroll
            for (int i = 0; i < 8; i++) {
                s[i]  += __shfl_xor(s[i], m);
                s2[i] += __shfl_xor(s2[i], m);
            }
#pragma unroll
        for (int i = 0; i < 8; i++)
            if (l16 == i) {
                int row = (i >> 2) * 16 + quad * 4 + (i & 3);
                psum[row * 5 + wave] = s[i];
                psq[row * 5 + wave]  = s2[i];
            }
    }
    __syncthreads();
    if (tid < 32) {
        float ss = 0.f, qq = 0.f;
#pragma unroll
        for (int p = 0; p < 4; p++) { ss += psum[tid * 5 + p]; qq += psq[tid * 5 + p]; }
        float mu = ss * 0.00390625f;
        float var = fmaxf(qq * 0.00390625f - mu * mu, 0.f);
        muA[tid] = mu;
        rsA[tid] = rsqrtf(var + 1e-5f);
    }
    __syncthreads();

    // ---- normalize acc -> normed bf16 [32][264] (aliases xs) ----
#pragma unroll
    for (int nt = 0; nt < 4; nt++) {
        int col = nsl + nt * 16 + l16;
        float g = gmm[col], bt = bta[col];
#pragma unroll
        for (int mf = 0; mf < 2; mf++)
#pragma unroll
            for (int r = 0; r < 4; r++) {
                int row = mf * 16 + quad * 4 + r;
                normed[row * 264 + col] =
                    f2bf((acc[mf][nt][r] - muA[row]) * rsA[row] * g + bt);
            }
    }
    __syncthreads();

    // ---- out = normed @ out_W + out_b ----
    floatx4 acc2[2][4];
#pragma unroll
    for (int i = 0; i < 2; i++)
#pragma unroll
        for (int j = 0; j < 4; j++) acc2[i][j] = {0.f, 0.f, 0.f, 0.f};
    gemm_tile<8>(normed, 264, outWT, 256, acc2, l16, quad, nsl);

    float* op = out + (size_t)m0 * 256;
#pragma unroll
    for (int nt = 0; nt < 4; nt++) {
        int col = nsl + nt * 16 + l16;
        float ob = outb[col];
#pragma unroll
        for (int mf = 0; mf < 2; mf++)
#pragma unroll
            for (int r = 0; r < 4; r++) {
                int row = mf * 16 + quad * 4 + r;
                op[row * 256 + col] = acc2[mf][nt][r] + ob;
            }
    }
}

// -------------------------------------------------------------- launch ----
extern "C" void kernel_launch(void* const* d_in, const int* in_sizes, int n_in,
                              void* d_out, int out_size, void* d_ws, size_t ws_size,
                              hipStream_t stream)
{
    (void)in_sizes; (void)n_in; (void)out_size; (void)ws_size;
    const float* x     = (const float*)d_in[0];
    const float* ck5   = (const float*)d_in[1];
    const float* ck9   = (const float*)d_in[2];
    const float* ck17  = (const float*)d_in[3];
    const float* projW = (const float*)d_in[4];
    const float* projb = (const float*)d_in[5];
    const float* rW    = (const float*)d_in[6];
    const float* rb    = (const float*)d_in[7];
    const float* outW  = (const float*)d_in[8];
    const float* outb  = (const float*)d_in[9];
    const float* gmm   = (const float*)d_in[10];
    const float* bta   = (const float*)d_in[11];

    __hip_bfloat16* projWT = (__hip_bfloat16*)d_ws;
    __hip_bfloat16* outWT  = (__hip_bfloat16*)((char*)d_ws + 1572864);
    __hip_bfloat16* projbT = (__hip_bfloat16*)((char*)d_ws + 1703936);
    __hip_bfloat16* rWT    = (__hip_bfloat16*)((char*)d_ws + 1720320);

    prep_kernel<<<dim3(209), dim3(256), 0, stream>>>(
        rW, projW, outW, projb, projWT, outWT, projbT, rWT);
    fused_kernel<<<dim3(512), dim3(256), 0, stream>>>(
        x, ck5, ck9, ck17, rb, gmm, bta, outb,
        projWT, outWT, projbT, rWT, (float*)d_out);
}

// Round 3
// 204.759 us; speedup vs baseline: 1.4546x; 1.0859x over previous
//
#include <hip/hip_runtime.h>
#include <hip/hip_bf16.h>

typedef short short8 __attribute__((ext_vector_type(8)));
typedef short short4_t __attribute__((ext_vector_type(4)));
typedef float floatx4 __attribute__((ext_vector_type(4)));

#define DEVI __device__ __forceinline__

// Dims: B=4, T=4096, D=256, E=12 (4x k5, 4x k9, 4x k17), 16384 tokens.
// fp32 in/out; MFMA operands bf16.
//
// R3: BM=64, 512-thread blocks, grid 256 = exactly 1 block/CU.
//   Rationale: grid size pinned VGPR cap at 128 (R2 spilled its B prefetch,
//   VGPR_Count==128 + 4MB scratch writes). At 1 block/CU the cap is 256:
//   whole-chunk register prefetch of B (dbuf, 64 VGPR) AND conv coeffs
//   (dbuf, 34 VGPR) now fit spill-free, issued one full chunk ahead of use.
//   B loads per MFMA halve vs BM=32; halo traffic and barriers per token
//   halve; per-thread conv amortization unchanged (16 outputs, R1 lesson).
//   As single-buffered to fit 64KB static LDS (2 barriers/chunk).
//
// ws: projWT bf16 [12][256f][256d] @ 0         (1,572,864)
//     outWT  bf16 [256f][256k]     @ 1,572,864 (131,072)
//     projbT bf16 [256n][32k]      @ 1,703,936 (16,384)  (k>=12 zero)
//     rWT    bf16 [16e][256d]      @ 1,720,320 (8,192)   (e>=12 zero)

DEVI float bf2f(__hip_bfloat16 v) { return __bfloat162float(v); }
DEVI __hip_bfloat16 f2bf(float v) { return __float2bfloat16(v); }
DEVI unsigned short bfbits(float v) { __hip_bfloat16 b = f2bf(v); return *(unsigned short*)&b; }

// ---------------------------------------------------------------- prep ----
// 209 blocks: 0..191 projW 64x64 transpose tiles, 192..207 outW, 208 misc.
__global__ __launch_bounds__(256) void prep_kernel(
    const float* __restrict__ rW,      // [256][12]
    const float* __restrict__ projW,   // [12][256d][256f]
    const float* __restrict__ outW,    // [256k][256f]
    const float* __restrict__ projb,   // [12][256]
    __hip_bfloat16* __restrict__ projWT,
    __hip_bfloat16* __restrict__ outWT,
    __hip_bfloat16* __restrict__ projbT,
    __hip_bfloat16* __restrict__ rWT)
{
    __shared__ __align__(16) __hip_bfloat16 Tt[64 * 72];
    const int bid = blockIdx.x;
    const int tid = threadIdx.x;

    if (bid == 208) {
#pragma unroll
        for (int k = 0; k < 32; k++)
            projbT[tid * 32 + k] = (k < 12) ? f2bf(projb[k * 256 + tid]) : f2bf(0.f);
#pragma unroll
        for (int e = 0; e < 16; e++)
            rWT[e * 256 + tid] = (e < 12) ? f2bf(rW[tid * 12 + e]) : f2bf(0.f);
        return;
    }
    const float* src;
    __hip_bfloat16* dst;
    if (bid < 192) {
        int e = bid >> 4, ti = (bid & 15) >> 2, tj = bid & 3;
        src = projW + (e << 16) + (ti * 64) * 256 + tj * 64;
        dst = projWT + (e << 16) + (tj * 64) * 256 + ti * 64;
    } else {
        int b3 = bid - 192, ti = b3 >> 2, tj = b3 & 3;
        src = outW + (ti * 64) * 256 + tj * 64;
        dst = outWT + (tj * 64) * 256 + ti * 64;
    }
#pragma unroll
    for (int i = 0; i < 4; i++) {
        int r = i * 16 + (tid >> 4);
        int c4 = (tid & 15) * 4;
        float4 f = *(const float4*)(src + r * 256 + c4);
        Tt[(c4 + 0) * 72 + r] = f2bf(f.x);
        Tt[(c4 + 1) * 72 + r] = f2bf(f.y);
        Tt[(c4 + 2) * 72 + r] = f2bf(f.z);
        Tt[(c4 + 3) * 72 + r] = f2bf(f.w);
    }
    __syncthreads();
#pragma unroll
    for (int i = 0; i < 2; i++) {
        int c = i * 32 + (tid >> 3);
        int r8 = (tid & 7) * 8;
        *(short8*)(dst + c * 256 + r8) = *(const short8*)(Tt + c * 72 + r8);
    }
}

// --------------------------------------------------------------- fused ----
// LDS map (62,720 B static, 1 block/CU):
//   xs    bf16 [80][264] @ 0       (42,240)  x tile incl. 16-row causal halo
//   As    bf16 [64][136] @ 42,240  (17,408)  A chunk (single buffer)
//   wts_s f32  [64][12]  @ 59,648  ( 3,072)
//   after chunk loop, aliased into xs region:
//   normed bf16 [64][264] @ 0      (33,792)
//   psum  f32 [64][9] @ 33,792 ; psq f32 [64][9] @ 36,096
//   muA   f32 [64]    @ 38,400 ; rsA f32 [64]   @ 38,656

template<int K>
DEVI void conv_lds(const float (&c)[17],                  // preloaded coeffs
                   const __hip_bfloat16* __restrict__ xs,
                   int tloc,
                   const float* __restrict__ wts_s, int e,
                   __hip_bfloat16* __restrict__ dst, int d_l, int d_g)
{
    float w[K - 1];
#pragma unroll
    for (int i = 0; i < K - 1; i++)
        w[i] = bf2f(xs[(16 + tloc - (K - 1) + i) * 264 + d_g]);
#pragma unroll
    for (int t = 0; t < 16; t++) {
        float nv = bf2f(xs[(16 + tloc + t) * 264 + d_g]);
        float s = nv * c[K - 1];
#pragma unroll
        for (int i = 0; i < K - 1; i++) s += w[i] * c[i];
        dst[(tloc + t) * 136 + d_l] = f2bf(s * wts_s[(tloc + t) * 12 + e]);
#pragma unroll
        for (int i = 0; i + 1 < K - 1; i++) w[i] = w[i + 1];
        w[K - 2] = nv;
    }
}

// GEMM with register-preloaded B: M=64 (4 m-frags) x N=32 (2 nt) x K=NKS*32.
template<int NKS>
DEVI void gemm_pre(const __hip_bfloat16* __restrict__ A,
                   const short8 (&B)[4][2], floatx4 (&acc)[4][2],
                   int l16, int quad)
{
    const __hip_bfloat16* ap = A + l16 * 136 + quad * 8;
    short8 a[4];
#pragma unroll
    for (int mf = 0; mf < 4; mf++) a[mf] = *(const short8*)(ap + mf * 16 * 136);
#pragma unroll
    for (int ks = 0; ks < NKS; ks++) {
        short8 na[4];
        if (ks < NKS - 1) {
#pragma unroll
            for (int mf = 0; mf < 4; mf++)
                na[mf] = *(const short8*)(ap + mf * 16 * 136 + (ks + 1) * 32);
        }
#pragma unroll
        for (int nt = 0; nt < 2; nt++)
#pragma unroll
            for (int mf = 0; mf < 4; mf++)
                acc[mf][nt] = __builtin_amdgcn_mfma_f32_16x16x32_bf16(
                    a[mf], B[ks][nt], acc[mf][nt], 0, 0, 0);
        if (ks < NKS - 1) {
#pragma unroll
            for (int mf = 0; mf < 4; mf++) a[mf] = na[mf];
        }
    }
}

// Out-projection GEMM: A=normed [64][264] in LDS, B=outWT from L2, K=256.
DEVI void gemm_out(const __hip_bfloat16* __restrict__ A,
                   const __hip_bfloat16* __restrict__ Bg,
                   floatx4 (&acc)[4][2], int l16, int quad, int nsl)
{
    const __hip_bfloat16* ap = A + l16 * 264 + quad * 8;
    const __hip_bfloat16* bp = Bg + (nsl + l16) * 256 + quad * 8;
    short8 a[4], b[2];
#pragma unroll
    for (int mf = 0; mf < 4; mf++) a[mf] = *(const short8*)(ap + mf * 16 * 264);
#pragma unroll
    for (int nt = 0; nt < 2; nt++) b[nt] = *(const short8*)(bp + nt * 16 * 256);
#pragma unroll
    for (int ks = 0; ks < 8; ks++) {
        short8 na[4], nb[2];
        if (ks < 7) {
#pragma unroll
            for (int mf = 0; mf < 4; mf++)
                na[mf] = *(const short8*)(ap + mf * 16 * 264 + (ks + 1) * 32);
#pragma unroll
            for (int nt = 0; nt < 2; nt++)
                nb[nt] = *(const short8*)(bp + nt * 16 * 256 + (ks + 1) * 32);
        }
#pragma unroll
        for (int nt = 0; nt < 2; nt++)
#pragma unroll
            for (int mf = 0; mf < 4; mf++)
                acc[mf][nt] = __builtin_amdgcn_mfma_f32_16x16x32_bf16(
                    a[mf], b[nt], acc[mf][nt], 0, 0, 0);
        if (ks < 7) {
#pragma unroll
            for (int mf = 0; mf < 4; mf++) a[mf] = na[mf];
#pragma unroll
            for (int nt = 0; nt < 2; nt++) b[nt] = nb[nt];
        }
    }
}

__global__ __launch_bounds__(512, 2) void fused_kernel(
    const float* __restrict__ x,
    const float* __restrict__ ck5, const float* __restrict__ ck9,
    const float* __restrict__ ck17,
    const float* __restrict__ rb,      // [12]
    const float* __restrict__ gmm, const float* __restrict__ bta,
    const float* __restrict__ outb,
    const __hip_bfloat16* __restrict__ projWT,
    const __hip_bfloat16* __restrict__ outWT,
    const __hip_bfloat16* __restrict__ projbT,
    const __hip_bfloat16* __restrict__ rWT,
    float* __restrict__ out)
{
    __shared__ __align__(16) char smem[62720];
    __hip_bfloat16* xs = (__hip_bfloat16*)smem;            // [80][264]
    __hip_bfloat16* As = (__hip_bfloat16*)(smem + 42240);  // [64][136]
    float* wts_s = (float*)(smem + 59648);                 // [64][12]
    __hip_bfloat16* normed = (__hip_bfloat16*)smem;        // [64][264] later
    float* psum = (float*)(smem + 33792);                  // [64][9] later
    float* psq  = (float*)(smem + 36096);                  // [64][9] later
    float* muA  = (float*)(smem + 38400);
    float* rsA  = (float*)(smem + 38656);

    const int tid  = threadIdx.x;
    const int wave = tid >> 6;                 // 0..7
    const int lane = tid & 63;
    const int quad = lane >> 4;
    const int l16  = lane & 15;
    const int nsl  = wave * 32;                // 32-wide f-slice per wave
    const int m0   = blockIdx.x * 64;
    const int bb   = m0 >> 12;
    const int t0   = m0 & 4095;

    // ---- stage x tile rows t0-16..t0+63, fp32 -> bf16 ----
    {
        const float* xb = x + (size_t)bb * 4096 * 256;
        for (int idx = tid; idx < 80 * 64; idx += 512) {
            int row = idx >> 6, c4 = (idx & 63) << 2;
            int gt = t0 - 16 + row;
            short4_t v = {0, 0, 0, 0};
            if (gt >= 0) {
                float4 f = *(const float4*)(xb + (size_t)gt * 256 + c4);
                v[0] = (short)bfbits(f.x); v[1] = (short)bfbits(f.y);
                v[2] = (short)bfbits(f.z); v[3] = (short)bfbits(f.w);
            }
            *(short4_t*)(xs + row * 264 + c4) = v;
        }
    }
    __syncthreads();

    // ---- router (waves 0..3, 16 rows each): MFMA logits + shuffle softmax ----
    if (wave < 4) {
        floatx4 ra = {0.f, 0.f, 0.f, 0.f};
        const __hip_bfloat16* ap = xs + (16 + wave * 16 + l16) * 264 + quad * 8;
        const __hip_bfloat16* bp = rWT + l16 * 256 + quad * 8;
#pragma unroll
        for (int kk = 0; kk < 256; kk += 32)
            ra = __builtin_amdgcn_mfma_f32_16x16x32_bf16(
                *(const short8*)(ap + kk), *(const short8*)(bp + kk), ra, 0, 0, 0);
        float rbv = (l16 < 12) ? rb[l16] : 0.f;
#pragma unroll
        for (int r = 0; r < 4; r++) {
            float v = (l16 < 12) ? (ra[r] + rbv) : -1e30f;
            float mx = v;
            mx = fmaxf(mx, __shfl_xor(mx, 1));
            mx = fmaxf(mx, __shfl_xor(mx, 2));
            mx = fmaxf(mx, __shfl_xor(mx, 4));
            mx = fmaxf(mx, __shfl_xor(mx, 8));
            float ex = (l16 < 12) ? __expf(v - mx) : 0.f;
            float sm = ex;
            sm += __shfl_xor(sm, 1);
            sm += __shfl_xor(sm, 2);
            sm += __shfl_xor(sm, 4);
            sm += __shfl_xor(sm, 8);
            if (l16 < 12) wts_s[(wave * 16 + quad * 4 + r) * 12 + l16] = ex / sm;
        }
    }
    __syncthreads();

    // ---- register prefetch helpers (one chunk ahead, no spills @256 cap) ----
    auto loadCoef = [&](float (&cr)[17], int c) {
        int e = c >> 1;
        int d_g = (c & 1) * 128 + (tid & 127);
        if (e < 4) {
            const float* cw = ck5 + e * 5 * 256;
#pragma unroll
            for (int j = 0; j < 5; j++) cr[j] = cw[j * 256 + d_g];
        } else if (e < 8) {
            const float* cw = ck9 + (e - 4) * 9 * 256;
#pragma unroll
            for (int j = 0; j < 9; j++) cr[j] = cw[j * 256 + d_g];
        } else {
            const float* cw = ck17 + (e - 8) * 17 * 256;
#pragma unroll
            for (int j = 0; j < 17; j++) cr[j] = cw[j * 256 + d_g];
        }
    };
    auto loadB = [&](short8 (&B)[4][2], int c) {
        if (c < 24) {
            int e = c >> 1, h = c & 1;
            const __hip_bfloat16* bp =
                projWT + (e << 16) + h * 128 + (nsl + l16) * 256 + quad * 8;
#pragma unroll
            for (int ks = 0; ks < 4; ks++)
#pragma unroll
                for (int nt = 0; nt < 2; nt++)
                    B[ks][nt] = *(const short8*)(bp + nt * 16 * 256 + ks * 32);
        } else {
            const __hip_bfloat16* bp = projbT + (nsl + l16) * 32 + quad * 8;
#pragma unroll
            for (int nt = 0; nt < 2; nt++)
                B[0][nt] = *(const short8*)(bp + nt * 16 * 32);
        }
    };
    auto produce = [&](int c, const float (&cr)[17]) {
        if (c == 24) {
            int t = tid >> 3, k4 = (tid & 7) * 4;
            short4_t v;
#pragma unroll
            for (int j = 0; j < 4; j++) {
                int k = k4 + j;
                v[j] = (k < 12) ? (short)bfbits(wts_s[t * 12 + k]) : (short)0;
            }
            *(short4_t*)(As + t * 136 + k4) = v;
        } else {
            int e = c >> 1;
            int d_l = tid & 127, tloc = (tid >> 7) * 16;
            int d_g = (c & 1) * 128 + d_l;
            if (e < 4)
                conv_lds<5>(cr, xs, tloc, wts_s, e, As, d_l, d_g);
            else if (e < 8)
                conv_lds<9>(cr, xs, tloc, wts_s, e, As, d_l, d_g);
            else
                conv_lds<17>(cr, xs, tloc, wts_s, e, As, d_l, d_g);
        }
    };

    floatx4 acc[4][2];
#pragma unroll
    for (int i = 0; i < 4; i++)
#pragma unroll
        for (int j = 0; j < 2; j++) acc[i][j] = {0.f, 0.f, 0.f, 0.f};

    float crA[17], crB[17];
    short8 BA[4][2], BB[4][2];

    loadB(BA, 0);
    loadCoef(crA, 0);
    produce(0, crA);
    __syncthreads();

    // 12 chunk pairs; B and coeffs for chunk c issued before gemm(c-1),
    // consumed after gemm + 2 barriers + produce -> latency fully covered.
#pragma unroll 1
    for (int cc = 0; cc < 12; cc++) {
        int c0 = 2 * cc;
        loadCoef(crB, c0 + 1);
        loadB(BB, c0 + 1);
        gemm_pre<4>(As, BA, acc, l16, quad);
        __syncthreads();                       // As consumed
        produce(c0 + 1, crB);
        __syncthreads();                       // As ready
        if (c0 + 2 < 24) loadCoef(crA, c0 + 2);
        loadB(BA, c0 + 2);                     // cc==11 -> bias B (projbT)
        gemm_pre<4>(As, BB, acc, l16, quad);
        __syncthreads();
        produce(c0 + 2, crA);                  // cc==11 -> bias chunk (cr unused)
        __syncthreads();
    }
    // bias chunk c=24
    gemm_pre<1>(As, BA, acc, l16, quad);

    // ---- LN stats from accumulators (exact fp32) ----
    {
        float s[16], s2[16];
#pragma unroll
        for (int mf = 0; mf < 4; mf++)
#pragma unroll
            for (int r = 0; r < 4; r++) {
                int i = mf * 4 + r;
                float v = 0.f, q = 0.f;
#pragma unroll
                for (int nt = 0; nt < 2; nt++) {
                    float a = acc[mf][nt][r];
                    v += a; q += a * a;
                }
                s[i] = v; s2[i] = q;
            }
#pragma unroll
        for (int m = 1; m <= 8; m <<= 1)
#pragma unroll
            for (int i = 0; i < 16; i++) {
                s[i]  += __shfl_xor(s[i], m);
                s2[i] += __shfl_xor(s2[i], m);
            }
#pragma unroll
        for (int i = 0; i < 16; i++)
            if (l16 == i) {
                int row = (i >> 2) * 16 + quad * 4 + (i & 3);
                psum[row * 9 + wave] = s[i];
                psq[row * 9 + wave]  = s2[i];
            }
    }
    __syncthreads();
    if (tid < 64) {
        float ss = 0.f, qq = 0.f;
#pragma unroll
        for (int p = 0; p < 8; p++) { ss += psum[tid * 9 + p]; qq += psq[tid * 9 + p]; }
        float mu = ss * 0.00390625f;
        float var = fmaxf(qq * 0.00390625f - mu * mu, 0.f);
        muA[tid] = mu;
        rsA[tid] = rsqrtf(var + 1e-5f);
    }
    __syncthreads();

    // ---- normalize acc -> normed bf16 [64][264] (aliases xs) ----
#pragma unroll
    for (int nt = 0; nt < 2; nt++) {
        int col = nsl + nt * 16 + l16;
        float g = gmm[col], bt = bta[col];
#pragma unroll
        for (int mf = 0; mf < 4; mf++)
#pragma unroll
            for (int r = 0; r < 4; r++) {
                int row = mf * 16 + quad * 4 + r;
                normed[row * 264 + col] =
                    f2bf((acc[mf][nt][r] - muA[row]) * rsA[row] * g + bt);
            }
    }
    __syncthreads();

    // ---- out = normed @ out_W + out_b ----
    floatx4 acc2[4][2];
#pragma unroll
    for (int i = 0; i < 4; i++)
#pragma unroll
        for (int j = 0; j < 2; j++) acc2[i][j] = {0.f, 0.f, 0.f, 0.f};
    gemm_out(normed, outWT, acc2, l16, quad, nsl);

    float* op = out + (size_t)m0 * 256;
#pragma unroll
    for (int nt = 0; nt < 2; nt++) {
        int col = nsl + nt * 16 + l16;
        float ob = outb[col];
#pragma unroll
        for (int mf = 0; mf < 4; mf++)
#pragma unroll
            for (int r = 0; r < 4; r++) {
                int row = mf * 16 + quad * 4 + r;
                op[row * 256 + col] = acc2[mf][nt][r] + ob;
            }
    }
}

// -------------------------------------------------------------- launch ----
extern "C" void kernel_launch(void* const* d_in, const int* in_sizes, int n_in,
                              void* d_out, int out_size, void* d_ws, size_t ws_size,
                              hipStream_t stream)
{
    (void)in_sizes; (void)n_in; (void)out_size; (void)ws_size;
    const float* x     = (const float*)d_in[0];
    const float* ck5   = (const float*)d_in[1];
    const float* ck9   = (const float*)d_in[2];
    const float* ck17  = (const float*)d_in[3];
    const float* projW = (const float*)d_in[4];
    const float* projb = (const float*)d_in[5];
    const float* rW    = (const float*)d_in[6];
    const float* rb    = (const float*)d_in[7];
    const float* outW  = (const float*)d_in[8];
    const float* outb  = (const float*)d_in[9];
    const float* gmm   = (const float*)d_in[10];
    const float* bta   = (const float*)d_in[11];

    __hip_bfloat16* projWT = (__hip_bfloat16*)d_ws;
    __hip_bfloat16* outWT  = (__hip_bfloat16*)((char*)d_ws + 1572864);
    __hip_bfloat16* projbT = (__hip_bfloat16*)((char*)d_ws + 1703936);
    __hip_bfloat16* rWT    = (__hip_bfloat16*)((char*)d_ws + 1720320);

    prep_kernel<<<dim3(209), dim3(256), 0, stream>>>(
        rW, projW, outW, projb, projWT, outWT, projbT, rWT);
    fused_kernel<<<dim3(256), dim3(512), 0, stream>>>(
        x, ck5, ck9, ck17, rb, gmm, bta, outb,
        projWT, outWT, projbT, rWT, (float*)d_out);
}

// Round 4
// 164.096 us; speedup vs baseline: 1.8150x; 1.2478x over previous
//
#include <hip/hip_runtime.h>
#include <hip/hip_bf16.h>

typedef short short8 __attribute__((ext_vector_type(8)));
typedef short short4_t __attribute__((ext_vector_type(4)));
typedef float floatx4 __attribute__((ext_vector_type(4)));

#define DEVI __device__ __forceinline__

// Dims: B=4, T=4096, D=256, E=12 (4x k5, 4x k9, 4x k17), 16384 tokens.
// fp32 in/out; MFMA operands bf16.
//
// R4: R3 shape (BM=64, 512 threads, grid 256, 1 blk/CU) with the register
//   prefetch actually allowed to live in registers:
//   - launch_bounds(512,1): R2/R3 proved the ",2" variant caps VGPR at ~128
//     (R2: VGPR==128+scratch; R3: VGPR==100 + 53MB scratch writes). Cap now
//     >=256; need ~190 -> no spill, occupancy unchanged (VGPR in 129..256
//     band -> 2 waves/SIMD -> 8 waves/CU -> 1 block, same as R3).
//   - loadCoef/loadB write their arrays FULLY on every path (zero-fill /
//     kstep=0) so SROA keeps them in registers (partial-extent writes under
//     runtime branches were the scratch trigger).
//
// ws: projWT bf16 [12][256f][256d] @ 0         (1,572,864)
//     outWT  bf16 [256f][256k]     @ 1,572,864 (131,072)
//     projbT bf16 [256n][32k]      @ 1,703,936 (16,384)  (k>=12 zero)
//     rWT    bf16 [16e][256d]      @ 1,720,320 (8,192)   (e>=12 zero)

DEVI float bf2f(__hip_bfloat16 v) { return __bfloat162float(v); }
DEVI __hip_bfloat16 f2bf(float v) { return __float2bfloat16(v); }
DEVI unsigned short bfbits(float v) { __hip_bfloat16 b = f2bf(v); return *(unsigned short*)&b; }

// ---------------------------------------------------------------- prep ----
// 209 blocks: 0..191 projW 64x64 transpose tiles, 192..207 outW, 208 misc.
__global__ __launch_bounds__(256) void prep_kernel(
    const float* __restrict__ rW,      // [256][12]
    const float* __restrict__ projW,   // [12][256d][256f]
    const float* __restrict__ outW,    // [256k][256f]
    const float* __restrict__ projb,   // [12][256]
    __hip_bfloat16* __restrict__ projWT,
    __hip_bfloat16* __restrict__ outWT,
    __hip_bfloat16* __restrict__ projbT,
    __hip_bfloat16* __restrict__ rWT)
{
    __shared__ __align__(16) __hip_bfloat16 Tt[64 * 72];
    const int bid = blockIdx.x;
    const int tid = threadIdx.x;

    if (bid == 208) {
#pragma unroll
        for (int k = 0; k < 32; k++)
            projbT[tid * 32 + k] = (k < 12) ? f2bf(projb[k * 256 + tid]) : f2bf(0.f);
#pragma unroll
        for (int e = 0; e < 16; e++)
            rWT[e * 256 + tid] = (e < 12) ? f2bf(rW[tid * 12 + e]) : f2bf(0.f);
        return;
    }
    const float* src;
    __hip_bfloat16* dst;
    if (bid < 192) {
        int e = bid >> 4, ti = (bid & 15) >> 2, tj = bid & 3;
        src = projW + (e << 16) + (ti * 64) * 256 + tj * 64;
        dst = projWT + (e << 16) + (tj * 64) * 256 + ti * 64;
    } else {
        int b3 = bid - 192, ti = b3 >> 2, tj = b3 & 3;
        src = outW + (ti * 64) * 256 + tj * 64;
        dst = outWT + (tj * 64) * 256 + ti * 64;
    }
#pragma unroll
    for (int i = 0; i < 4; i++) {
        int r = i * 16 + (tid >> 4);
        int c4 = (tid & 15) * 4;
        float4 f = *(const float4*)(src + r * 256 + c4);
        Tt[(c4 + 0) * 72 + r] = f2bf(f.x);
        Tt[(c4 + 1) * 72 + r] = f2bf(f.y);
        Tt[(c4 + 2) * 72 + r] = f2bf(f.z);
        Tt[(c4 + 3) * 72 + r] = f2bf(f.w);
    }
    __syncthreads();
#pragma unroll
    for (int i = 0; i < 2; i++) {
        int c = i * 32 + (tid >> 3);
        int r8 = (tid & 7) * 8;
        *(short8*)(dst + c * 256 + r8) = *(const short8*)(Tt + c * 72 + r8);
    }
}

// --------------------------------------------------------------- fused ----
// LDS map (62,720 B static, 1 block/CU):
//   xs    bf16 [80][264] @ 0       (42,240)  x tile incl. 16-row causal halo
//   As    bf16 [64][136] @ 42,240  (17,408)  A chunk (single buffer)
//   wts_s f32  [64][12]  @ 59,648  ( 3,072)
//   after chunk loop, aliased into xs region:
//   normed bf16 [64][264] @ 0      (33,792)
//   psum  f32 [64][9] @ 33,792 ; psq f32 [64][9] @ 36,096
//   muA   f32 [64]    @ 38,400 ; rsA f32 [64]   @ 38,656

template<int K>
DEVI void conv_lds(const float (&c)[17],                  // preloaded coeffs
                   const __hip_bfloat16* __restrict__ xs,
                   int tloc,
                   const float* __restrict__ wts_s, int e,
                   __hip_bfloat16* __restrict__ dst, int d_l, int d_g)
{
    float w[K - 1];
#pragma unroll
    for (int i = 0; i < K - 1; i++)
        w[i] = bf2f(xs[(16 + tloc - (K - 1) + i) * 264 + d_g]);
#pragma unroll
    for (int t = 0; t < 16; t++) {
        float nv = bf2f(xs[(16 + tloc + t) * 264 + d_g]);
        float s = nv * c[K - 1];
#pragma unroll
        for (int i = 0; i < K - 1; i++) s += w[i] * c[i];
        dst[(tloc + t) * 136 + d_l] = f2bf(s * wts_s[(tloc + t) * 12 + e]);
#pragma unroll
        for (int i = 0; i + 1 < K - 1; i++) w[i] = w[i + 1];
        w[K - 2] = nv;
    }
}

// GEMM with register-preloaded B: M=64 (4 m-frags) x N=32 (2 nt) x K=NKS*32.
template<int NKS>
DEVI void gemm_pre(const __hip_bfloat16* __restrict__ A,
                   const short8 (&B)[4][2], floatx4 (&acc)[4][2],
                   int l16, int quad)
{
    const __hip_bfloat16* ap = A + l16 * 136 + quad * 8;
    short8 a[4];
#pragma unroll
    for (int mf = 0; mf < 4; mf++) a[mf] = *(const short8*)(ap + mf * 16 * 136);
#pragma unroll
    for (int ks = 0; ks < NKS; ks++) {
        short8 na[4];
        if (ks < NKS - 1) {
#pragma unroll
            for (int mf = 0; mf < 4; mf++)
                na[mf] = *(const short8*)(ap + mf * 16 * 136 + (ks + 1) * 32);
        }
#pragma unroll
        for (int nt = 0; nt < 2; nt++)
#pragma unroll
            for (int mf = 0; mf < 4; mf++)
                acc[mf][nt] = __builtin_amdgcn_mfma_f32_16x16x32_bf16(
                    a[mf], B[ks][nt], acc[mf][nt], 0, 0, 0);
        if (ks < NKS - 1) {
#pragma unroll
            for (int mf = 0; mf < 4; mf++) a[mf] = na[mf];
        }
    }
}

// Out-projection GEMM: A=normed [64][264] in LDS, B=outWT from L2, K=256.
DEVI void gemm_out(const __hip_bfloat16* __restrict__ A,
                   const __hip_bfloat16* __restrict__ Bg,
                   floatx4 (&acc)[4][2], int l16, int quad, int nsl)
{
    const __hip_bfloat16* ap = A + l16 * 264 + quad * 8;
    const __hip_bfloat16* bp = Bg + (nsl + l16) * 256 + quad * 8;
    short8 a[4], b[2];
#pragma unroll
    for (int mf = 0; mf < 4; mf++) a[mf] = *(const short8*)(ap + mf * 16 * 264);
#pragma unroll
    for (int nt = 0; nt < 2; nt++) b[nt] = *(const short8*)(bp + nt * 16 * 256);
#pragma unroll
    for (int ks = 0; ks < 8; ks++) {
        short8 na[4], nb[2];
        if (ks < 7) {
#pragma unroll
            for (int mf = 0; mf < 4; mf++)
                na[mf] = *(const short8*)(ap + mf * 16 * 264 + (ks + 1) * 32);
#pragma unroll
            for (int nt = 0; nt < 2; nt++)
                nb[nt] = *(const short8*)(bp + nt * 16 * 256 + (ks + 1) * 32);
        }
#pragma unroll
        for (int nt = 0; nt < 2; nt++)
#pragma unroll
            for (int mf = 0; mf < 4; mf++)
                acc[mf][nt] = __builtin_amdgcn_mfma_f32_16x16x32_bf16(
                    a[mf], b[nt], acc[mf][nt], 0, 0, 0);
        if (ks < 7) {
#pragma unroll
            for (int mf = 0; mf < 4; mf++) a[mf] = na[mf];
#pragma unroll
            for (int nt = 0; nt < 2; nt++) b[nt] = nb[nt];
        }
    }
}

__global__ __launch_bounds__(512, 1) void fused_kernel(
    const float* __restrict__ x,
    const float* __restrict__ ck5, const float* __restrict__ ck9,
    const float* __restrict__ ck17,
    const float* __restrict__ rb,      // [12]
    const float* __restrict__ gmm, const float* __restrict__ bta,
    const float* __restrict__ outb,
    const __hip_bfloat16* __restrict__ projWT,
    const __hip_bfloat16* __restrict__ outWT,
    const __hip_bfloat16* __restrict__ projbT,
    const __hip_bfloat16* __restrict__ rWT,
    float* __restrict__ out)
{
    __shared__ __align__(16) char smem[62720];
    __hip_bfloat16* xs = (__hip_bfloat16*)smem;            // [80][264]
    __hip_bfloat16* As = (__hip_bfloat16*)(smem + 42240);  // [64][136]
    float* wts_s = (float*)(smem + 59648);                 // [64][12]
    __hip_bfloat16* normed = (__hip_bfloat16*)smem;        // [64][264] later
    float* psum = (float*)(smem + 33792);                  // [64][9] later
    float* psq  = (float*)(smem + 36096);                  // [64][9] later
    float* muA  = (float*)(smem + 38400);
    float* rsA  = (float*)(smem + 38656);

    const int tid  = threadIdx.x;
    const int wave = tid >> 6;                 // 0..7
    const int lane = tid & 63;
    const int quad = lane >> 4;
    const int l16  = lane & 15;
    const int nsl  = wave * 32;                // 32-wide f-slice per wave
    const int m0   = blockIdx.x * 64;
    const int bb   = m0 >> 12;
    const int t0   = m0 & 4095;

    // ---- stage x tile rows t0-16..t0+63, fp32 -> bf16 ----
    {
        const float* xb = x + (size_t)bb * 4096 * 256;
        for (int idx = tid; idx < 80 * 64; idx += 512) {
            int row = idx >> 6, c4 = (idx & 63) << 2;
            int gt = t0 - 16 + row;
            short4_t v = {0, 0, 0, 0};
            if (gt >= 0) {
                float4 f = *(const float4*)(xb + (size_t)gt * 256 + c4);
                v[0] = (short)bfbits(f.x); v[1] = (short)bfbits(f.y);
                v[2] = (short)bfbits(f.z); v[3] = (short)bfbits(f.w);
            }
            *(short4_t*)(xs + row * 264 + c4) = v;
        }
    }
    __syncthreads();

    // ---- router (waves 0..3, 16 rows each): MFMA logits + shuffle softmax ----
    if (wave < 4) {
        floatx4 ra = {0.f, 0.f, 0.f, 0.f};
        const __hip_bfloat16* ap = xs + (16 + wave * 16 + l16) * 264 + quad * 8;
        const __hip_bfloat16* bp = rWT + l16 * 256 + quad * 8;
#pragma unroll
        for (int kk = 0; kk < 256; kk += 32)
            ra = __builtin_amdgcn_mfma_f32_16x16x32_bf16(
                *(const short8*)(ap + kk), *(const short8*)(bp + kk), ra, 0, 0, 0);
        float rbv = (l16 < 12) ? rb[l16] : 0.f;
#pragma unroll
        for (int r = 0; r < 4; r++) {
            float v = (l16 < 12) ? (ra[r] + rbv) : -1e30f;
            float mx = v;
            mx = fmaxf(mx, __shfl_xor(mx, 1));
            mx = fmaxf(mx, __shfl_xor(mx, 2));
            mx = fmaxf(mx, __shfl_xor(mx, 4));
            mx = fmaxf(mx, __shfl_xor(mx, 8));
            float ex = (l16 < 12) ? __expf(v - mx) : 0.f;
            float sm = ex;
            sm += __shfl_xor(sm, 1);
            sm += __shfl_xor(sm, 2);
            sm += __shfl_xor(sm, 4);
            sm += __shfl_xor(sm, 8);
            if (l16 < 12) wts_s[(wave * 16 + quad * 4 + r) * 12 + l16] = ex / sm;
        }
    }
    __syncthreads();

    // ---- register prefetch helpers -------------------------------------
    // Full-extent writes on every path (scratch-trigger avoidance, R2/R3).
    auto loadCoef = [&](float (&cr)[17], int c) {
        int e = c >> 1;
        int d_g = (c & 1) * 128 + (tid & 127);
        if (e < 4) {
            const float* cw = ck5 + e * 5 * 256;
#pragma unroll
            for (int j = 0; j < 17; j++) cr[j] = (j < 5) ? cw[j * 256 + d_g] : 0.f;
        } else if (e < 8) {
            const float* cw = ck9 + (e - 4) * 9 * 256;
#pragma unroll
            for (int j = 0; j < 17; j++) cr[j] = (j < 9) ? cw[j * 256 + d_g] : 0.f;
        } else {
            const float* cw = ck17 + (e - 8) * 17 * 256;
#pragma unroll
            for (int j = 0; j < 17; j++) cr[j] = cw[j * 256 + d_g];
        }
    };
    auto loadB = [&](short8 (&B)[4][2], int c) {
        const __hip_bfloat16* bp;
        int rs, kstep;
        if (c < 24) {
            int e = c >> 1, h = c & 1;
            bp = projWT + (e << 16) + h * 128 + (nsl + l16) * 256 + quad * 8;
            rs = 256; kstep = 32;
        } else {
            bp = projbT + (nsl + l16) * 32 + quad * 8;
            rs = 32; kstep = 0;             // all ks read same (only ks=0 used)
        }
#pragma unroll
        for (int ks = 0; ks < 4; ks++)
#pragma unroll
            for (int nt = 0; nt < 2; nt++)
                B[ks][nt] = *(const short8*)(bp + nt * 16 * rs + ks * kstep);
    };
    auto produce = [&](int c, const float (&cr)[17]) {
        if (c == 24) {
            int t = tid >> 3, k4 = (tid & 7) * 4;
            short4_t v;
#pragma unroll
            for (int j = 0; j < 4; j++) {
                int k = k4 + j;
                v[j] = (k < 12) ? (short)bfbits(wts_s[t * 12 + k]) : (short)0;
            }
            *(short4_t*)(As + t * 136 + k4) = v;
        } else {
            int e = c >> 1;
            int d_l = tid & 127, tloc = (tid >> 7) * 16;
            int d_g = (c & 1) * 128 + d_l;
            if (e < 4)
                conv_lds<5>(cr, xs, tloc, wts_s, e, As, d_l, d_g);
            else if (e < 8)
                conv_lds<9>(cr, xs, tloc, wts_s, e, As, d_l, d_g);
            else
                conv_lds<17>(cr, xs, tloc, wts_s, e, As, d_l, d_g);
        }
    };

    floatx4 acc[4][2];
#pragma unroll
    for (int i = 0; i < 4; i++)
#pragma unroll
        for (int j = 0; j < 2; j++) acc[i][j] = {0.f, 0.f, 0.f, 0.f};

    float crA[17], crB[17];
    short8 BA[4][2], BB[4][2];

    loadB(BA, 0);
    loadCoef(crA, 0);
    produce(0, crA);
    __syncthreads();

    // 12 chunk pairs; B and coeffs for chunk c issued before gemm(c-1),
    // consumed after gemm + 2 barriers + produce -> latency fully covered.
#pragma unroll 1
    for (int cc = 0; cc < 12; cc++) {
        int c0 = 2 * cc;
        loadCoef(crB, c0 + 1);
        loadB(BB, c0 + 1);
        gemm_pre<4>(As, BA, acc, l16, quad);
        __syncthreads();                       // As consumed
        produce(c0 + 1, crB);
        __syncthreads();                       // As ready
        if (c0 + 2 < 24) loadCoef(crA, c0 + 2);
        loadB(BA, c0 + 2);                     // cc==11 -> bias B (projbT)
        gemm_pre<4>(As, BB, acc, l16, quad);
        __syncthreads();
        produce(c0 + 2, crA);                  // cc==11 -> bias chunk (cr unused)
        __syncthreads();
    }
    // bias chunk c=24
    gemm_pre<1>(As, BA, acc, l16, quad);

    // ---- LN stats from accumulators (exact fp32) ----
    {
        float s[16], s2[16];
#pragma unroll
        for (int mf = 0; mf < 4; mf++)
#pragma unroll
            for (int r = 0; r < 4; r++) {
                int i = mf * 4 + r;
                float v = 0.f, q = 0.f;
#pragma unroll
                for (int nt = 0; nt < 2; nt++) {
                    float a = acc[mf][nt][r];
                    v += a; q += a * a;
                }
                s[i] = v; s2[i] = q;
            }
#pragma unroll
        for (int m = 1; m <= 8; m <<= 1)
#pragma unroll
            for (int i = 0; i < 16; i++) {
                s[i]  += __shfl_xor(s[i], m);
                s2[i] += __shfl_xor(s2[i], m);
            }
#pragma unroll
        for (int i = 0; i < 16; i++)
            if (l16 == i) {
                int row = (i >> 2) * 16 + quad * 4 + (i & 3);
                psum[row * 9 + wave] = s[i];
                psq[row * 9 + wave]  = s2[i];
            }
    }
    __syncthreads();
    if (tid < 64) {
        float ss = 0.f, qq = 0.f;
#pragma unroll
        for (int p = 0; p < 8; p++) { ss += psum[tid * 9 + p]; qq += psq[tid * 9 + p]; }
        float mu = ss * 0.00390625f;
        float var = fmaxf(qq * 0.00390625f - mu * mu, 0.f);
        muA[tid] = mu;
        rsA[tid] = rsqrtf(var + 1e-5f);
    }
    __syncthreads();

    // ---- normalize acc -> normed bf16 [64][264] (aliases xs) ----
#pragma unroll
    for (int nt = 0; nt < 2; nt++) {
        int col = nsl + nt * 16 + l16;
        float g = gmm[col], bt = bta[col];
#pragma unroll
        for (int mf = 0; mf < 4; mf++)
#pragma unroll
            for (int r = 0; r < 4; r++) {
                int row = mf * 16 + quad * 4 + r;
                normed[row * 264 + col] =
                    f2bf((acc[mf][nt][r] - muA[row]) * rsA[row] * g + bt);
            }
    }
    __syncthreads();

    // ---- out = normed @ out_W + out_b ----
    floatx4 acc2[4][2];
#pragma unroll
    for (int i = 0; i < 4; i++)
#pragma unroll
        for (int j = 0; j < 2; j++) acc2[i][j] = {0.f, 0.f, 0.f, 0.f};
    gemm_out(normed, outWT, acc2, l16, quad, nsl);

    float* op = out + (size_t)m0 * 256;
#pragma unroll
    for (int nt = 0; nt < 2; nt++) {
        int col = nsl + nt * 16 + l16;
        float ob = outb[col];
#pragma unroll
        for (int mf = 0; mf < 4; mf++)
#pragma unroll
            for (int r = 0; r < 4; r++) {
                int row = mf * 16 + quad * 4 + r;
                op[row * 256 + col] = acc2[mf][nt][r] + ob;
            }
    }
}

// -------------------------------------------------------------- launch ----
extern "C" void kernel_launch(void* const* d_in, const int* in_sizes, int n_in,
                              void* d_out, int out_size, void* d_ws, size_t ws_size,
                              hipStream_t stream)
{
    (void)in_sizes; (void)n_in; (void)out_size; (void)ws_size;
    const float* x     = (const float*)d_in[0];
    const float* ck5   = (const float*)d_in[1];
    const float* ck9   = (const float*)d_in[2];
    const float* ck17  = (const float*)d_in[3];
    const float* projW = (const float*)d_in[4];
    const float* projb = (const float*)d_in[5];
    const float* rW    = (const float*)d_in[6];
    const float* rb    = (const float*)d_in[7];
    const float* outW  = (const float*)d_in[8];
    const float* outb  = (const float*)d_in[9];
    const float* gmm   = (const float*)d_in[10];
    const float* bta   = (const float*)d_in[11];

    __hip_bfloat16* projWT = (__hip_bfloat16*)d_ws;
    __hip_bfloat16* outWT  = (__hip_bfloat16*)((char*)d_ws + 1572864);
    __hip_bfloat16* projbT = (__hip_bfloat16*)((char*)d_ws + 1703936);
    __hip_bfloat16* rWT    = (__hip_bfloat16*)((char*)d_ws + 1720320);

    prep_kernel<<<dim3(209), dim3(256), 0, stream>>>(
        rW, projW, outW, projb, projWT, outWT, projbT, rWT);
    fused_kernel<<<dim3(256), dim3(512), 0, stream>>>(
        x, ck5, ck9, ck17, rb, gmm, bta, outb,
        projWT, outWT, projbT, rWT, (float*)d_out);
}